// Round 1
// 154.606 us; speedup vs baseline: 1.0512x; 1.0512x over previous
//
#include <hip/hip_runtime.h>

typedef _Float16 half2v __attribute__((ext_vector_type(2)));

// ---- prep: zero stats buffer + convert w_span fp32 -> fp16 (feeds k_main) ----
__global__ void k_prep(const float* __restrict__ wspan, _Float16* __restrict__ w16,
                       float* __restrict__ stats){
  int i = blockIdx.x * 256 + threadIdx.x;
  if (i < 32) stats[i] = 0.f;                      // block 0 zeroes BN stats
  if (i < 12544) w16[i] = (_Float16)wspan[i];
}

// ---- fused front-end v3: dw3x3 + pw1x1 + reduce1x1 + BN stats ----
// 8x8 px tile, 1024 blocks (4/CU). wave = full tile (lane=px).
// Per 16-ch chunk q: wave w stages ITS OWN 4 channels (wave-private s_in4[w],
// no barrier needed for the stage->dw handoff), register-prefetches chunk q+1
// before computing q (global latency hidden under dw+pw), then the s_dw4
// cross-wave handoff keeps 2 barriers per q (8/block vs 12 before).
__launch_bounds__(256, 4)
__global__ void k_front(const float* __restrict__ in, const float* __restrict__ wdw,
                        const float* __restrict__ wpw, const float* __restrict__ wred,
                        float* __restrict__ h, float* __restrict__ r,
                        float* __restrict__ stats){
  __shared__ float4 s_in4[4][10][12];              // [wave][ry][rx] 4ch contiguous
  __shared__ float4 s_dw4[4][64];                  // [c4][px]
  __shared__ float4 s_cv4[4][64];                  // [c4][px] raw center vals
  __shared__ float  s_red[4][8];
  int t = threadIdx.x;
  int w = t >> 6, lane = t & 63;
  int lx = lane & 7, ly = lane >> 3;
  int blk = blockIdx.x;
  blk = ((blk & 7) << 7) | (blk >> 3);             // XCD-contiguous remap (bijective, 1024=8*128)
  int tile = blk & 255, b = blk >> 8;
  int x0 = (tile & 15) << 3, y0 = (tile >> 4) << 3;
  const float* inb = in + ((long)b << 20) + ((long)(w << 2) << 14);

  // per-wave halo staging: wave w owns c4 == w. 100 halo points, lane does {lane, lane+64}.
  int p0 = lane, p1 = lane + 64;
  int ry0 = p0 / 10, rx0 = p0 - ry0 * 10;
  int ry1 = p1 / 10, rx1 = p1 - ry1 * 10;
  int yy0 = y0 + ry0 - 1, xx0 = x0 + rx0 - 1;
  int yy1 = y0 + ry1 - 1, xx1 = x0 + rx1 - 1;
  bool ok0 = (unsigned)yy0 < 128u && (unsigned)xx0 < 128u;
  bool ok1 = (p1 < 100) && ((unsigned)yy1 < 128u) && ((unsigned)xx1 < 128u);
  int o0 = (yy0 << 7) + xx0, o1 = (yy1 << 7) + xx1;

  float pacc[16], racc[4];
  #pragma unroll
  for (int j = 0; j < 16; j++) pacc[j] = 0.f;
  #pragma unroll
  for (int j = 0; j < 4; j++) racc[j] = 0.f;

  // prologue: prefetch q=0 into registers
  float4 v0 = make_float4(0.f, 0.f, 0.f, 0.f), v1 = make_float4(0.f, 0.f, 0.f, 0.f);
  if (ok0){ v0.x = inb[o0]; v0.y = inb[o0 + 16384]; v0.z = inb[o0 + 32768]; v0.w = inb[o0 + 49152]; }
  if (ok1){ v1.x = inb[o1]; v1.y = inb[o1 + 16384]; v1.z = inb[o1 + 32768]; v1.w = inb[o1 + 49152]; }

  for (int q = 0; q < 4; q++){
    // commit prefetched regs to wave-private LDS region (no cross-wave hazard)
    s_in4[w][ry0][rx0] = v0;
    if (p1 < 100) s_in4[w][ry1][rx1] = v1;
    __builtin_amdgcn_wave_barrier();               // keep dw reads after these writes

    // issue q+1 prefetch now; latency hides under dw+pw below
    if (q < 3){
      const float* pq = inb + ((long)(q + 1) << 18);   // +16 channels
      v0 = make_float4(0.f, 0.f, 0.f, 0.f); v1 = make_float4(0.f, 0.f, 0.f, 0.f);
      if (ok0){ v0.x = pq[o0]; v0.y = pq[o0 + 16384]; v0.z = pq[o0 + 32768]; v0.w = pq[o0 + 49152]; }
      if (ok1){ v1.x = pq[o1]; v1.y = pq[o1 + 16384]; v1.z = pq[o1 + 32768]; v1.w = pq[o1 + 49152]; }
    }

    // dw: wave w convolves its 4 channels (same-wave LDS data, in-order DS pipe)
    const float* wd = wdw + ((q << 4) + (w << 2)) * 9;   // uniform -> s_load
    float4 a = make_float4(0.f, 0.f, 0.f, 0.f);
    float4 cv = make_float4(0.f, 0.f, 0.f, 0.f);
    #pragma unroll
    for (int dy = 0; dy < 3; dy++){
      #pragma unroll
      for (int dx = 0; dx < 3; dx++){
        float4 v = s_in4[w][ly + dy][lx + dx];
        int k = dy * 3 + dx;
        a.x += v.x * wd[k];
        a.y += v.y * wd[9 + k];
        a.z += v.z * wd[18 + k];
        a.w += v.w * wd[27 + k];
        if (k == 4) cv = v;
      }
    }

    __syncthreads();                               // pw(q-1) done reading s_dw4
    s_dw4[w][lane] = a;
    s_cv4[w][lane] = cv;
    __syncthreads();                               // s_dw4/s_cv4 ready

    float4 d0 = s_dw4[0][lane], d1 = s_dw4[1][lane];
    float4 d2 = s_dw4[2][lane], d3 = s_dw4[3][lane];
    float4 e0 = s_cv4[0][lane], e1 = s_cv4[1][lane];
    float4 e2 = s_cv4[2][lane], e3 = s_cv4[3][lane];
    int c0 = q << 4;
    #pragma unroll
    for (int j = 0; j < 16; j++){
      const float* wr = wpw + ((w << 4) + j) * 64 + c0;  // uniform -> s_load
      float s = pacc[j];
      s += d0.x * wr[0]  + d0.y * wr[1]  + d0.z * wr[2]  + d0.w * wr[3];
      s += d1.x * wr[4]  + d1.y * wr[5]  + d1.z * wr[6]  + d1.w * wr[7];
      s += d2.x * wr[8]  + d2.y * wr[9]  + d2.z * wr[10] + d2.w * wr[11];
      s += d3.x * wr[12] + d3.y * wr[13] + d3.z * wr[14] + d3.w * wr[15];
      pacc[j] = s;
    }
    #pragma unroll
    for (int j = 0; j < 4; j++){
      const float* wr = wred + ((w << 2) + j) * 64 + c0;
      float s = racc[j];
      s += e0.x * wr[0]  + e0.y * wr[1]  + e0.z * wr[2]  + e0.w * wr[3];
      s += e1.x * wr[4]  + e1.y * wr[5]  + e1.z * wr[6]  + e1.w * wr[7];
      s += e2.x * wr[8]  + e2.y * wr[9]  + e2.z * wr[10] + e2.w * wr[11];
      s += e3.x * wr[12] + e3.y * wr[13] + e3.z * wr[14] + e3.w * wr[15];
      racc[j] = s;
    }
  }

  long sp = ((long)(y0 + ly) << 7) + x0 + lx;
  float* hb = h + ((long)b << 20) + sp;
  #pragma unroll
  for (int j = 0; j < 16; j++) hb[(long)((w << 4) + j) << 14] = pacc[j];
  float* rb = r + ((long)b << 18) + sp;
  #pragma unroll
  for (int j = 0; j < 4; j++) rb[(long)((w << 2) + j) << 14] = racc[j];

  // BN stats: wave w owns channels 4w..4w+3
  #pragma unroll
  for (int j = 0; j < 4; j++){
    float v = racc[j], s2 = racc[j] * racc[j];
    #pragma unroll
    for (int off = 32; off > 0; off >>= 1){
      v  += __shfl_down(v,  off, 64);
      s2 += __shfl_down(s2, off, 64);
    }
    if (lane == 0){ s_red[w][2 * j] = v; s_red[w][2 * j + 1] = s2; }
  }
  __syncthreads();
  if (t < 32) atomicAdd(&stats[t], s_red[t >> 3][t & 7]);
}

// ---- main involution: per (b, g, 16x16 tile); BN finalize inlined ----
__launch_bounds__(256)
__global__ void k_main(const float* __restrict__ h, const float* __restrict__ r,
                       const float* __restrict__ stats, const float* __restrict__ gamma,
                       const float* __restrict__ beta, const _Float16* __restrict__ w16,
                       float* __restrict__ out){
  __shared__ float4 s_h4[22][24];                  // [row][col] -> 4 cg contiguous
  __shared__ float  s_sb[32];
  int t = threadIdx.x;
  int g = blockIdx.y, b = blockIdx.z;
  int bx = blockIdx.x;
  bx = ((bx & 7) << 3) | (bx >> 3);                // XCD-contiguous remap (bijective, 64=8*8)
  int tx0 = (bx & 7) << 4, ty0 = (bx >> 3) << 4;

  // issue r loads early; consumed after the barrier
  int ltx = t & 15, lty = t >> 4;
  int px = tx0 + ltx, py = ty0 + lty;
  const float* rp = r + ((long)b << 18) + (py << 7) + px;
  float rraw[16];
  #pragma unroll
  for (int c = 0; c < 16; c++) rraw[c] = rp[(long)c << 14];

  const float* hp = h + (((long)(b * 64 + g * 4)) << 14);
  for (int p = t; p < 484; p += 256){              // 22x22 halo points
    int ry = p / 22, rx = p - ry * 22;
    int yy = ty0 + ry - 3, xx = tx0 + rx - 3;
    float4 v = make_float4(0.f, 0.f, 0.f, 0.f);
    if ((unsigned)yy < 128u && (unsigned)xx < 128u){
      int o = (yy << 7) + xx;
      v.x = hp[o];
      v.y = hp[o + 16384];
      v.z = hp[o + 32768];
      v.w = hp[o + 49152];
    }
    s_h4[ry][rx] = v;
  }

  // BN finalize (training-mode, biased var) done per-block: kills the k_bn dispatch
  if (t < 16){
    const float inv_n = 1.52587890625e-5f;         // 1/65536 (exact)
    float mean = stats[2 * t] * inv_n;
    float var  = stats[2 * t + 1] * inv_n - mean * mean;
    float inv  = rsqrtf(var + 1e-5f);
    float sc   = gamma[t] * inv;
    s_sb[2 * t]     = sc;
    s_sb[2 * t + 1] = beta[t] - mean * sc;
  }
  __syncthreads();

  float rv[16];
  #pragma unroll
  for (int c = 0; c < 16; c++)
    rv[c] = fmaxf(rraw[c] * s_sb[2 * c] + s_sb[2 * c + 1], 0.f);
#if __has_builtin(__builtin_amdgcn_fdot2)
  half2v rv2[8];
  #pragma unroll
  for (int j = 0; j < 8; j++){
    half2v pk; pk[0] = (_Float16)rv[2 * j]; pk[1] = (_Float16)rv[2 * j + 1];
    rv2[j] = pk;
  }
#endif

  const _Float16* wg = w16 + g * 784;              // uniform -> scalar pipe
#if __has_builtin(__builtin_amdgcn_fdot2)
  const half2v* wg2 = (const half2v*)wg;
#endif
  float acc0 = 0.f, acc1 = 0.f, acc2 = 0.f, acc3 = 0.f;
  #pragma unroll
  for (int kh = 0; kh < 7; kh++){
    #pragma unroll
    for (int kw = 0; kw < 7; kw++){
      int k = kh * 7 + kw;
      float kv = 0.f;
#if __has_builtin(__builtin_amdgcn_fdot2)
      #pragma unroll
      for (int j = 0; j < 8; j++)
        kv = __builtin_amdgcn_fdot2(rv2[j], wg2[k * 8 + j], kv, false);
#else
      #pragma unroll
      for (int c = 0; c < 16; c++) kv += rv[c] * (float)wg[k * 16 + c];
#endif
      float4 hv = s_h4[lty + kh][ltx + kw];
      acc0 += kv * hv.x;
      acc1 += kv * hv.y;
      acc2 += kv * hv.z;
      acc3 += kv * hv.w;
    }
  }

  long obase = (((long)(b * 64 + g * 4)) << 14) + (py << 7) + px;
  out[obase]         = acc0;
  out[obase + 16384] = acc1;
  out[obase + 32768] = acc2;
  out[obase + 49152] = acc3;
}

extern "C" void kernel_launch(void* const* d_in, const int* in_sizes, int n_in,
                              void* d_out, int out_size, void* d_ws, size_t ws_size,
                              hipStream_t stream){
  const float* in       = (const float*)d_in[0];
  const float* w_dw     = (const float*)d_in[1];
  const float* w_pw     = (const float*)d_in[2];
  const float* gamma    = (const float*)d_in[3];
  const float* beta     = (const float*)d_in[4];
  const float* w_reduce = (const float*)d_in[5];
  const float* w_span   = (const float*)d_in[6];
  float* out = (float*)d_out;

  float* ws    = (float*)d_ws;
  float* h     = ws;                    // 4194304 floats
  float* r     = ws + 4194304;          // 1048576 floats
  float* stats = ws + 5242880;          // 32 floats
  _Float16* w16 = (_Float16*)(ws + 5242944);  // 12544 halfs

  k_prep <<<49, 256, 0, stream>>>(w_span, w16, stats);
  k_front<<<1024, 256, 0, stream>>>(in, w_dw, w_pw, w_reduce, h, r, stats);
  dim3 grid(64, 16, 4);
  k_main <<<grid, 256, 0, stream>>>(h, r, stats, gamma, beta, w16, out);
}

// Round 2
// 126.222 us; speedup vs baseline: 1.2876x; 1.2249x over previous
//
#include <hip/hip_runtime.h>

typedef _Float16 half2v __attribute__((ext_vector_type(2)));
typedef _Float16 half4v __attribute__((ext_vector_type(4)));
typedef _Float16 half8v __attribute__((ext_vector_type(8)));
typedef float f32x4 __attribute__((ext_vector_type(4)));

// ---- prep: zero stats buffer + convert w_span fp32 -> fp16 (feeds k_main) ----
__global__ void k_prep(const float* __restrict__ wspan, _Float16* __restrict__ w16,
                       float* __restrict__ stats){
  int i = blockIdx.x * 256 + threadIdx.x;
  if (i < 32) stats[i] = 0.f;                      // block 0 zeroes BN stats
  if (i < 12544) w16[i] = (_Float16)wspan[i];
}

// ---- fused front-end v4: dw3x3 (VALU) + pw1x1/red1x1 (MFMA) + BN stats ----
// 8x8 px tile, 1024 blocks (4/CU), 4 waves. q-loop has NO barriers: wave w
// stages its own s_in4[w], dw-convs its 4 channels, deposits fp16 dw-out and
// center vals transposed into s_dwh/s_cvh[px][c]. Then ONE barrier and the
// 64x64x64 pw GEMM + 16x64x64 red GEMM run on MFMA with weight A-fragments
// loaded once per block (kills the per-q per-j weight refetch stalls of v3).
__launch_bounds__(256, 4)
__global__ void k_front(const float* __restrict__ in, const float* __restrict__ wdw,
                        const float* __restrict__ wpw, const float* __restrict__ wred,
                        float* __restrict__ h, float* __restrict__ r,
                        float* __restrict__ stats){
  __shared__ float4 s_in4[4][10][12];              // [wave][ry][rx] 4ch contiguous
  __shared__ __attribute__((aligned(16))) _Float16 s_dwh[64][72];  // [px][c] dw out
  __shared__ __attribute__((aligned(16))) _Float16 s_cvh[64][72];  // [px][c] center vals
  __shared__ float s_red[4][32];
  int t = threadIdx.x;
  int w = t >> 6, lane = t & 63;
  int lx = lane & 7, ly = lane >> 3;
  int c15 = lane & 15, hi = lane >> 4;
  int blk = blockIdx.x;
  blk = ((blk & 7) << 7) | (blk >> 3);             // XCD-contiguous remap (bijective)
  int tile = blk & 255, b = blk >> 8;
  int x0 = (tile & 15) << 3, y0 = (tile >> 4) << 3;
  const float* inb = in + ((long)b << 20) + ((long)(w << 2) << 14);

  // ---- A-fragments: loaded ONCE per block (per-lane vector loads) ----
  // pw: wave w owns o-rows 16w..16w+15. A[row=lane&15][k=(lane>>4)*8+j], kf = K/32 half
  const float* ap = wpw + (((w << 4) + c15) << 6) + (hi << 3);
  float4 ap0 = *(const float4*)(ap);
  float4 ap1 = *(const float4*)(ap + 4);
  float4 ap2 = *(const float4*)(ap + 32);
  float4 ap3 = *(const float4*)(ap + 36);
  const float* arp = wred + (c15 << 6) + (hi << 3);
  float4 ar0 = *(const float4*)(arp);
  float4 ar1 = *(const float4*)(arp + 4);
  float4 ar2 = *(const float4*)(arp + 32);
  float4 ar3 = *(const float4*)(arp + 36);
  half8v a_pw0 = {(_Float16)ap0.x,(_Float16)ap0.y,(_Float16)ap0.z,(_Float16)ap0.w,
                  (_Float16)ap1.x,(_Float16)ap1.y,(_Float16)ap1.z,(_Float16)ap1.w};
  half8v a_pw1 = {(_Float16)ap2.x,(_Float16)ap2.y,(_Float16)ap2.z,(_Float16)ap2.w,
                  (_Float16)ap3.x,(_Float16)ap3.y,(_Float16)ap3.z,(_Float16)ap3.w};
  half8v a_rd0 = {(_Float16)ar0.x,(_Float16)ar0.y,(_Float16)ar0.z,(_Float16)ar0.w,
                  (_Float16)ar1.x,(_Float16)ar1.y,(_Float16)ar1.z,(_Float16)ar1.w};
  half8v a_rd1 = {(_Float16)ar2.x,(_Float16)ar2.y,(_Float16)ar2.z,(_Float16)ar2.w,
                  (_Float16)ar3.x,(_Float16)ar3.y,(_Float16)ar3.z,(_Float16)ar3.w};

  // ---- per-wave halo staging geometry (wave w owns channel group w) ----
  int p0 = lane, p1 = lane + 64;
  int ry0 = p0 / 10, rx0 = p0 - ry0 * 10;
  int ry1 = p1 / 10, rx1 = p1 - ry1 * 10;
  int yy0 = y0 + ry0 - 1, xx0 = x0 + rx0 - 1;
  int yy1 = y0 + ry1 - 1, xx1 = x0 + rx1 - 1;
  bool ok0 = (unsigned)yy0 < 128u && (unsigned)xx0 < 128u;
  bool ok1 = (p1 < 100) && ((unsigned)yy1 < 128u) && ((unsigned)xx1 < 128u);
  int o0 = (yy0 << 7) + xx0, o1 = (yy1 << 7) + xx1;

  // prologue: prefetch q=0 into registers
  float4 v0 = make_float4(0.f, 0.f, 0.f, 0.f), v1 = make_float4(0.f, 0.f, 0.f, 0.f);
  if (ok0){ v0.x = inb[o0]; v0.y = inb[o0 + 16384]; v0.z = inb[o0 + 32768]; v0.w = inb[o0 + 49152]; }
  if (ok1){ v1.x = inb[o1]; v1.y = inb[o1 + 16384]; v1.z = inb[o1 + 32768]; v1.w = inb[o1 + 49152]; }

  for (int q = 0; q < 4; q++){
    s_in4[w][ry0][rx0] = v0;
    if (p1 < 100) s_in4[w][ry1][rx1] = v1;
    __builtin_amdgcn_wave_barrier();               // keep dw reads after these writes

    if (q < 3){                                    // issue q+1 prefetch; hides under dw
      const float* pq = inb + ((long)(q + 1) << 18);
      v0 = make_float4(0.f, 0.f, 0.f, 0.f); v1 = make_float4(0.f, 0.f, 0.f, 0.f);
      if (ok0){ v0.x = pq[o0]; v0.y = pq[o0 + 16384]; v0.z = pq[o0 + 32768]; v0.w = pq[o0 + 49152]; }
      if (ok1){ v1.x = pq[o1]; v1.y = pq[o1 + 16384]; v1.z = pq[o1 + 32768]; v1.w = pq[o1 + 49152]; }
    }

    // dw: wave w convolves its 4 channels (wave-private LDS, no block barrier)
    int wdbase = __builtin_amdgcn_readfirstlane(((q << 4) + (w << 2)) * 9);
    const float* wd = wdw + wdbase;                // forced scalar path
    float4 a = make_float4(0.f, 0.f, 0.f, 0.f);
    float4 cv = make_float4(0.f, 0.f, 0.f, 0.f);
    #pragma unroll
    for (int dy = 0; dy < 3; dy++){
      #pragma unroll
      for (int dx = 0; dx < 3; dx++){
        float4 v = s_in4[w][ly + dy][lx + dx];
        int k = dy * 3 + dx;
        a.x += v.x * wd[k];
        a.y += v.y * wd[9 + k];
        a.z += v.z * wd[18 + k];
        a.w += v.w * wd[27 + k];
        if (k == 4) cv = v;
      }
    }

    // deposit fp16, transposed [px][c]; wave w writes only its channel columns
    int cb = (q << 4) + (w << 2);
    half4v ah = {(_Float16)a.x, (_Float16)a.y, (_Float16)a.z, (_Float16)a.w};
    half4v eh = {(_Float16)cv.x, (_Float16)cv.y, (_Float16)cv.z, (_Float16)cv.w};
    *(half4v*)&s_dwh[lane][cb] = ah;
    *(half4v*)&s_cvh[lane][cb] = eh;
  }

  __syncthreads();                                 // all 64 channels deposited

  // ---- pw GEMM: wave w computes o-tile w (16 o x 64 px, K=64) = 8 MFMAs ----
  f32x4 z = {0.f, 0.f, 0.f, 0.f};
  f32x4 acc[4] = {z, z, z, z};
  #pragma unroll
  for (int tt = 0; tt < 4; tt++){
    half8v b0 = *(const half8v*)&s_dwh[(tt << 4) + c15][hi << 3];
    half8v b1 = *(const half8v*)&s_dwh[(tt << 4) + c15][32 + (hi << 3)];
    acc[tt] = __builtin_amdgcn_mfma_f32_16x16x32_f16(a_pw0, b0, acc[tt], 0, 0, 0);
    acc[tt] = __builtin_amdgcn_mfma_f32_16x16x32_f16(a_pw1, b1, acc[tt], 0, 0, 0);
  }
  // D: row(o_local) = 4*hi + reg, col(px) = 16*tt + c15
  #pragma unroll
  for (int tt = 0; tt < 4; tt++){
    int px = (tt << 4) + c15, py = px >> 3, pxl = px & 7;
    long base = ((long)((b << 6) + (w << 4) + (hi << 2)) << 14) + ((y0 + py) << 7) + x0 + pxl;
    #pragma unroll
    for (int rr = 0; rr < 4; rr++) h[base + ((long)rr << 14)] = acc[tt][rr];
  }

  // ---- red GEMM: wave w computes px-tile w (16 ch x 16 px, K=64) = 2 MFMAs ----
  f32x4 rac = z;
  {
    half8v b0 = *(const half8v*)&s_cvh[(w << 4) + c15][hi << 3];
    half8v b1 = *(const half8v*)&s_cvh[(w << 4) + c15][32 + (hi << 3)];
    rac = __builtin_amdgcn_mfma_f32_16x16x32_f16(a_rd0, b0, rac, 0, 0, 0);
    rac = __builtin_amdgcn_mfma_f32_16x16x32_f16(a_rd1, b1, rac, 0, 0, 0);
  }
  {
    int px = (w << 4) + c15, py = px >> 3, pxl = px & 7;
    long rbase = ((long)b << 18) + ((long)(hi << 2) << 14) + ((y0 + py) << 7) + x0 + pxl;
    #pragma unroll
    for (int rr = 0; rr < 4; rr++) r[rbase + ((long)rr << 14)] = rac[rr];
  }

  // ---- BN stats: reduce over this wave's 16 px (low 4 lane bits), combine ----
  #pragma unroll
  for (int rr = 0; rr < 4; rr++){
    float v = rac[rr], s2 = v * v;
    #pragma unroll
    for (int m = 1; m < 16; m <<= 1){
      v  += __shfl_xor(v,  m, 64);
      s2 += __shfl_xor(s2, m, 64);
    }
    if (c15 == 0){
      int ch = (hi << 2) + rr;
      s_red[w][2 * ch]     = v;
      s_red[w][2 * ch + 1] = s2;
    }
  }
  __syncthreads();
  if (t < 32){
    float sum = s_red[0][t] + s_red[1][t] + s_red[2][t] + s_red[3][t];
    atomicAdd(&stats[t], sum);
  }
}

// ---- main involution: per (b, g, 16x16 tile); BN finalize inlined ----
__launch_bounds__(256)
__global__ void k_main(const float* __restrict__ h, const float* __restrict__ r,
                       const float* __restrict__ stats, const float* __restrict__ gamma,
                       const float* __restrict__ beta, const _Float16* __restrict__ w16,
                       float* __restrict__ out){
  __shared__ float4 s_h4[22][24];                  // [row][col] -> 4 cg contiguous
  __shared__ float  s_sb[32];
  int t = threadIdx.x;
  int g = blockIdx.y, b = blockIdx.z;
  int bx = blockIdx.x;
  bx = ((bx & 7) << 3) | (bx >> 3);                // XCD-contiguous remap (bijective)
  int tx0 = (bx & 7) << 4, ty0 = (bx >> 3) << 4;

  // issue r loads early; consumed after the barrier
  int ltx = t & 15, lty = t >> 4;
  int px = tx0 + ltx, py = ty0 + lty;
  const float* rp = r + ((long)b << 18) + (py << 7) + px;
  float rraw[16];
  #pragma unroll
  for (int c = 0; c < 16; c++) rraw[c] = rp[(long)c << 14];

  const float* hp = h + (((long)(b * 64 + g * 4)) << 14);
  for (int p = t; p < 484; p += 256){              // 22x22 halo points
    int ry = p / 22, rx = p - ry * 22;
    int yy = ty0 + ry - 3, xx = tx0 + rx - 3;
    float4 v = make_float4(0.f, 0.f, 0.f, 0.f);
    if ((unsigned)yy < 128u && (unsigned)xx < 128u){
      int o = (yy << 7) + xx;
      v.x = hp[o];
      v.y = hp[o + 16384];
      v.z = hp[o + 32768];
      v.w = hp[o + 49152];
    }
    s_h4[ry][rx] = v;
  }

  // BN finalize (training-mode, biased var) per-block
  if (t < 16){
    const float inv_n = 1.52587890625e-5f;         // 1/65536 (exact)
    float mean = stats[2 * t] * inv_n;
    float var  = stats[2 * t + 1] * inv_n - mean * mean;
    float inv  = rsqrtf(var + 1e-5f);
    float sc   = gamma[t] * inv;
    s_sb[2 * t]     = sc;
    s_sb[2 * t + 1] = beta[t] - mean * sc;
  }
  __syncthreads();

  float rv[16];
  #pragma unroll
  for (int c = 0; c < 16; c++)
    rv[c] = fmaxf(rraw[c] * s_sb[2 * c] + s_sb[2 * c + 1], 0.f);
#if __has_builtin(__builtin_amdgcn_fdot2)
  half2v rv2[8];
  #pragma unroll
  for (int j = 0; j < 8; j++){
    half2v pk; pk[0] = (_Float16)rv[2 * j]; pk[1] = (_Float16)rv[2 * j + 1];
    rv2[j] = pk;
  }
#endif

  const _Float16* wg = w16 + g * 784;              // uniform -> scalar pipe
#if __has_builtin(__builtin_amdgcn_fdot2)
  const half2v* wg2 = (const half2v*)wg;
#endif
  float acc0 = 0.f, acc1 = 0.f, acc2 = 0.f, acc3 = 0.f;
  #pragma unroll
  for (int kh = 0; kh < 7; kh++){
    #pragma unroll
    for (int kw = 0; kw < 7; kw++){
      int k = kh * 7 + kw;
      float kv = 0.f;
#if __has_builtin(__builtin_amdgcn_fdot2)
      #pragma unroll
      for (int j = 0; j < 8; j++)
        kv = __builtin_amdgcn_fdot2(rv2[j], wg2[k * 8 + j], kv, false);
#else
      #pragma unroll
      for (int c = 0; c < 16; c++) kv += rv[c] * (float)wg[k * 16 + c];
#endif
      float4 hv = s_h4[lty + kh][ltx + kw];
      acc0 += kv * hv.x;
      acc1 += kv * hv.y;
      acc2 += kv * hv.z;
      acc3 += kv * hv.w;
    }
  }

  long obase = (((long)(b * 64 + g * 4)) << 14) + (py << 7) + px;
  out[obase]         = acc0;
  out[obase + 16384] = acc1;
  out[obase + 32768] = acc2;
  out[obase + 49152] = acc3;
}

extern "C" void kernel_launch(void* const* d_in, const int* in_sizes, int n_in,
                              void* d_out, int out_size, void* d_ws, size_t ws_size,
                              hipStream_t stream){
  const float* in       = (const float*)d_in[0];
  const float* w_dw     = (const float*)d_in[1];
  const float* w_pw     = (const float*)d_in[2];
  const float* gamma    = (const float*)d_in[3];
  const float* beta     = (const float*)d_in[4];
  const float* w_reduce = (const float*)d_in[5];
  const float* w_span   = (const float*)d_in[6];
  float* out = (float*)d_out;

  float* ws    = (float*)d_ws;
  float* h     = ws;                    // 4194304 floats
  float* r     = ws + 4194304;          // 1048576 floats
  float* stats = ws + 5242880;          // 32 floats
  _Float16* w16 = (_Float16*)(ws + 5242944);  // 12544 halfs

  k_prep <<<49, 256, 0, stream>>>(w_span, w16, stats);
  k_front<<<1024, 256, 0, stream>>>(in, w_dw, w_pw, w_reduce, h, r, stats);
  dim3 grid(64, 16, 4);
  k_main <<<grid, 256, 0, stream>>>(h, r, stats, gamma, beta, w16, out);
}

// Round 4
// 125.078 us; speedup vs baseline: 1.2994x; 1.0092x over previous
//
#include <hip/hip_runtime.h>

typedef _Float16 half2v __attribute__((ext_vector_type(2)));
typedef _Float16 half4v __attribute__((ext_vector_type(4)));
typedef _Float16 half8v __attribute__((ext_vector_type(8)));
typedef float f32x4 __attribute__((ext_vector_type(4)));

// ---- fused front-end: dw3x3 (VALU) + pw1x1/red1x1 (MFMA) + BN stats ----
// 8x8 px tile, 1024 blocks (4/CU), 4 waves. q-loop barrier-free (wave-private
// s_in4[w]); one block barrier before the MFMA phase. Weight A-fragments
// loaded once per block. Intermediates stored fp16 in consumer layouts:
//   h16[b][g][y][x][4cg]  (D-frag rr=0..3 = one cg group -> one 8B store)
//   r16[b][y][x][16ch]    (k_main reads all 16 ch as 2x16B)
// Blocks 0..48 also convert w_span -> fp16 (consumed by k_main next dispatch).
__launch_bounds__(256, 4)
__global__ void k_front(const float* __restrict__ in, const float* __restrict__ wdw,
                        const float* __restrict__ wpw, const float* __restrict__ wred,
                        const float* __restrict__ wspan,
                        _Float16* __restrict__ h16, _Float16* __restrict__ r16,
                        float* __restrict__ stats, _Float16* __restrict__ w16){
  __shared__ float4 s_in4[4][10][12];              // [wave][ry][rx] 4ch contiguous
  __shared__ __attribute__((aligned(16))) _Float16 s_dwh[64][72];  // [px][c]
  __shared__ __attribute__((aligned(16))) _Float16 s_cvh[64][72];  // [px][c]
  __shared__ float s_red[4][32];
  int t = threadIdx.x;
  int w = t >> 6, lane = t & 63;
  int lx = lane & 7, ly = lane >> 3;
  int c15 = lane & 15, hi = lane >> 4;
  int blk0 = blockIdx.x;

  // fold k_prep: w_span fp32 -> fp16 (12544 elems, blocks 0..48)
  {
    int i = blk0 * 256 + t;
    if (i < 12544) w16[i] = (_Float16)wspan[i];
  }

  int blk = ((blk0 & 7) << 7) | (blk0 >> 3);       // XCD-contiguous remap (bijective)
  int tile = blk & 255, b = blk >> 8;
  int x0 = (tile & 15) << 3, y0 = (tile >> 4) << 3;
  const float* inb = in + ((long)b << 20) + ((long)(w << 2) << 14);

  // ---- A-fragments loaded once: pw rows 16w..16w+15, red rows 0..15 ----
  const float* ap = wpw + (((w << 4) + c15) << 6) + (hi << 3);
  float4 ap0 = *(const float4*)(ap);
  float4 ap1 = *(const float4*)(ap + 4);
  float4 ap2 = *(const float4*)(ap + 32);
  float4 ap3 = *(const float4*)(ap + 36);
  const float* arp = wred + (c15 << 6) + (hi << 3);
  float4 ar0 = *(const float4*)(arp);
  float4 ar1 = *(const float4*)(arp + 4);
  float4 ar2 = *(const float4*)(arp + 32);
  float4 ar3 = *(const float4*)(arp + 36);
  half8v a_pw0 = {(_Float16)ap0.x,(_Float16)ap0.y,(_Float16)ap0.z,(_Float16)ap0.w,
                  (_Float16)ap1.x,(_Float16)ap1.y,(_Float16)ap1.z,(_Float16)ap1.w};
  half8v a_pw1 = {(_Float16)ap2.x,(_Float16)ap2.y,(_Float16)ap2.z,(_Float16)ap2.w,
                  (_Float16)ap3.x,(_Float16)ap3.y,(_Float16)ap3.z,(_Float16)ap3.w};
  half8v a_rd0 = {(_Float16)ar0.x,(_Float16)ar0.y,(_Float16)ar0.z,(_Float16)ar0.w,
                  (_Float16)ar1.x,(_Float16)ar1.y,(_Float16)ar1.z,(_Float16)ar1.w};
  half8v a_rd1 = {(_Float16)ar2.x,(_Float16)ar2.y,(_Float16)ar2.z,(_Float16)ar2.w,
                  (_Float16)ar3.x,(_Float16)ar3.y,(_Float16)ar3.z,(_Float16)ar3.w};

  // ---- per-wave halo staging: wave w owns channel group w; 100 pts, 2/lane ----
  int p1 = lane + 64;
  int ry0 = lane / 10, rx0 = lane - ry0 * 10;
  int ry1 = p1 / 10,   rx1 = p1 - ry1 * 10;
  int yy0 = y0 + ry0 - 1, xx0 = x0 + rx0 - 1;
  int yy1 = y0 + ry1 - 1, xx1 = x0 + rx1 - 1;
  bool ok0 = (unsigned)yy0 < 128u && (unsigned)xx0 < 128u;
  bool ok1 = (p1 < 100) && ((unsigned)yy1 < 128u) && ((unsigned)xx1 < 128u);
  int o0 = (yy0 << 7) + xx0, o1 = (yy1 << 7) + xx1;

  float4 v0 = make_float4(0.f,0.f,0.f,0.f), v1 = make_float4(0.f,0.f,0.f,0.f);
  if (ok0){ v0.x = inb[o0]; v0.y = inb[o0+16384]; v0.z = inb[o0+32768]; v0.w = inb[o0+49152]; }
  if (ok1){ v1.x = inb[o1]; v1.y = inb[o1+16384]; v1.z = inb[o1+32768]; v1.w = inb[o1+49152]; }

  for (int q = 0; q < 4; q++){
    s_in4[w][ry0][rx0] = v0;
    if (p1 < 100) s_in4[w][ry1][rx1] = v1;
    __builtin_amdgcn_wave_barrier();               // keep dw reads after these writes

    if (q < 3){                                    // prefetch q+1; hides under dw
      const float* pq = inb + ((long)(q + 1) << 18);
      v0 = make_float4(0.f,0.f,0.f,0.f); v1 = make_float4(0.f,0.f,0.f,0.f);
      if (ok0){ v0.x = pq[o0]; v0.y = pq[o0+16384]; v0.z = pq[o0+32768]; v0.w = pq[o0+49152]; }
      if (ok1){ v1.x = pq[o1]; v1.y = pq[o1+16384]; v1.z = pq[o1+32768]; v1.w = pq[o1+49152]; }
    }

    int wdbase = __builtin_amdgcn_readfirstlane(((q << 4) + (w << 2)) * 9);
    const float* wd = wdw + wdbase;                // forced scalar path
    float4 a = make_float4(0.f,0.f,0.f,0.f);
    float4 cv = make_float4(0.f,0.f,0.f,0.f);
    #pragma unroll
    for (int dy = 0; dy < 3; dy++){
      #pragma unroll
      for (int dx = 0; dx < 3; dx++){
        float4 v = s_in4[w][ly + dy][lx + dx];
        int k = dy * 3 + dx;
        a.x += v.x * wd[k];
        a.y += v.y * wd[9 + k];
        a.z += v.z * wd[18 + k];
        a.w += v.w * wd[27 + k];
        if (k == 4) cv = v;
      }
    }
    int cb = (q << 4) + (w << 2);
    half4v ah = {(_Float16)a.x,(_Float16)a.y,(_Float16)a.z,(_Float16)a.w};
    half4v eh = {(_Float16)cv.x,(_Float16)cv.y,(_Float16)cv.z,(_Float16)cv.w};
    *(half4v*)&s_dwh[lane][cb] = ah;
    *(half4v*)&s_cvh[lane][cb] = eh;
  }

  __syncthreads();                                 // all 64 channels deposited

  // ---- pw GEMM: wave w -> o-rows 16w..16w+15, 64 px, K=64 (8 MFMAs) ----
  f32x4 z = {0.f,0.f,0.f,0.f};
  f32x4 acc[4] = {z, z, z, z};
  #pragma unroll
  for (int tt = 0; tt < 4; tt++){
    half8v b0 = *(const half8v*)&s_dwh[(tt << 4) + c15][hi << 3];
    half8v b1 = *(const half8v*)&s_dwh[(tt << 4) + c15][32 + (hi << 3)];
    acc[tt] = __builtin_amdgcn_mfma_f32_16x16x32_f16(a_pw0, b0, acc[tt], 0, 0, 0);
    acc[tt] = __builtin_amdgcn_mfma_f32_16x16x32_f16(a_pw1, b1, acc[tt], 0, 0, 0);
  }
  // D: ch = 16w+4hi+rr (4 consecutive = group g=4w+hi), col px = 16tt+c15
  #pragma unroll
  for (int tt = 0; tt < 4; tt++){
    int px = (tt << 4) + c15;
    int pyl = px >> 3, pxl = px & 7;
    int gout = (w << 2) + hi;
    long off = ((((long)((b << 4) + gout)) << 14) + ((y0 + pyl) << 7) + x0 + pxl) << 2;
    half4v hv = {(_Float16)acc[tt][0], (_Float16)acc[tt][1],
                 (_Float16)acc[tt][2], (_Float16)acc[tt][3]};
    *(half4v*)&h16[off] = hv;
  }

  // ---- red GEMM: wave w -> px-tile w (16 ch x 16 px, K=64) = 2 MFMAs ----
  f32x4 rac = z;
  {
    half8v b0 = *(const half8v*)&s_cvh[(w << 4) + c15][hi << 3];
    half8v b1 = *(const half8v*)&s_cvh[(w << 4) + c15][32 + (hi << 3)];
    rac = __builtin_amdgcn_mfma_f32_16x16x32_f16(a_rd0, b0, rac, 0, 0, 0);
    rac = __builtin_amdgcn_mfma_f32_16x16x32_f16(a_rd1, b1, rac, 0, 0, 0);
  }
  {
    int px = (w << 4) + c15;
    int pyl = px >> 3, pxl = px & 7;
    long roff = ((((long)b << 14) + ((y0 + pyl) << 7) + x0 + pxl) << 4) + (hi << 2);
    half4v rv4 = {(_Float16)rac[0], (_Float16)rac[1], (_Float16)rac[2], (_Float16)rac[3]};
    *(half4v*)&r16[roff] = rv4;
  }

  // ---- BN stats from fp32 regs: wave-reduce over 16 px, combine, atomic ----
  #pragma unroll
  for (int rr = 0; rr < 4; rr++){
    float v = rac[rr], s2 = v * v;
    #pragma unroll
    for (int m = 1; m < 16; m <<= 1){
      v  += __shfl_xor(v,  m, 64);
      s2 += __shfl_xor(s2, m, 64);
    }
    if (c15 == 0){
      int ch = (hi << 2) + rr;
      s_red[w][2 * ch]     = v;
      s_red[w][2 * ch + 1] = s2;
    }
  }
  __syncthreads();
  if (t < 32){
    float sum = s_red[0][t] + s_red[1][t] + s_red[2][t] + s_red[3][t];
    atomicAdd(&stats[t], sum);
  }
}

// ---- main involution: per (b, g, 16x16 tile); BN finalize inlined ----
__launch_bounds__(256)
__global__ void k_main(const _Float16* __restrict__ h16, const _Float16* __restrict__ r16,
                       const float* __restrict__ stats, const float* __restrict__ gamma,
                       const float* __restrict__ beta, const _Float16* __restrict__ w16,
                       float* __restrict__ out){
  __shared__ float4 s_h4[22][24];                  // halo [row][col] fp32
  __shared__ float  s_sb[32];
  int t = threadIdx.x;
  int g = blockIdx.y, b = blockIdx.z;
  int bx = blockIdx.x;
  bx = ((bx & 7) << 3) | (bx >> 3);                // XCD-contiguous remap (bijective)
  int tx0 = (bx & 7) << 4, ty0 = (bx >> 3) << 4;

  int ltx = t & 15, lty = t >> 4;
  int px = tx0 + ltx, py = ty0 + lty;

  // r: all 16 channels contiguous -> 2x16B loads, issued early
  const _Float16* rp = r16 + ((((long)b << 14) + (py << 7) + px) << 4);
  half8v ra = *(const half8v*)rp;
  half8v rb = *(const half8v*)(rp + 8);

  // h halo: one 8B half4 load per point (4 cg channels contiguous)
  const _Float16* hp = h16 + (((long)((b << 4) + g)) << 16);
  for (int p = t; p < 484; p += 256){              // 22x22 halo points
    int ry = p / 22, rx = p - ry * 22;
    int yy = ty0 + ry - 3, xx = tx0 + rx - 3;
    float4 v = make_float4(0.f,0.f,0.f,0.f);
    if ((unsigned)yy < 128u && (unsigned)xx < 128u){
      half4v hh = *(const half4v*)&hp[(long)(((yy << 7) + xx) << 2)];
      v = make_float4((float)hh[0], (float)hh[1], (float)hh[2], (float)hh[3]);
    }
    s_h4[ry][rx] = v;
  }

  // BN finalize (training-mode, biased var) per-block
  if (t < 16){
    const float inv_n = 1.52587890625e-5f;         // 1/65536 (exact)
    float mean = stats[2 * t] * inv_n;
    float var  = stats[2 * t + 1] * inv_n - mean * mean;
    float inv  = rsqrtf(var + 1e-5f);
    float sc   = gamma[t] * inv;
    s_sb[2 * t]     = sc;
    s_sb[2 * t + 1] = beta[t] - mean * sc;
  }
  __syncthreads();

  float rv[16];
  #pragma unroll
  for (int c = 0; c < 8; c++){
    rv[c]     = fmaxf((float)ra[c] * s_sb[2*c]     + s_sb[2*c+1],     0.f);
    rv[c + 8] = fmaxf((float)rb[c] * s_sb[2*(c+8)] + s_sb[2*(c+8)+1], 0.f);
  }
#if __has_builtin(__builtin_amdgcn_fdot2)
  half2v rv2[8];
  #pragma unroll
  for (int j = 0; j < 8; j++){
    half2v pk; pk[0] = (_Float16)rv[2*j]; pk[1] = (_Float16)rv[2*j+1];
    rv2[j] = pk;
  }
#endif

  const _Float16* wg = w16 + g * 784;              // uniform -> scalar pipe
#if __has_builtin(__builtin_amdgcn_fdot2)
  const half2v* wg2 = (const half2v*)wg;
#endif
  float acc0 = 0.f, acc1 = 0.f, acc2 = 0.f, acc3 = 0.f;
  #pragma unroll
  for (int kh = 0; kh < 7; kh++){
    #pragma unroll
    for (int kw = 0; kw < 7; kw++){
      int k = kh * 7 + kw;
      float kv0 = 0.f, kv1 = 0.f;                  // split dep chain (2x4 deep)
#if __has_builtin(__builtin_amdgcn_fdot2)
      #pragma unroll
      for (int j = 0; j < 4; j++){
        kv0 = __builtin_amdgcn_fdot2(rv2[j],     wg2[k*8 + j],     kv0, false);
        kv1 = __builtin_amdgcn_fdot2(rv2[j + 4], wg2[k*8 + j + 4], kv1, false);
      }
#else
      #pragma unroll
      for (int c = 0; c < 8; c++){
        kv0 += rv[c]     * (float)wg[k*16 + c];
        kv1 += rv[c + 8] * (float)wg[k*16 + c + 8];
      }
#endif
      float kv = kv0 + kv1;
      float4 hv = s_h4[lty + kh][ltx + kw];
      acc0 += kv * hv.x;
      acc1 += kv * hv.y;
      acc2 += kv * hv.z;
      acc3 += kv * hv.w;
    }
  }

  long obase = (((long)((b << 6) + (g << 2))) << 14) + (py << 7) + px;
  out[obase]         = acc0;
  out[obase + 16384] = acc1;
  out[obase + 32768] = acc2;
  out[obase + 49152] = acc3;
}

extern "C" void kernel_launch(void* const* d_in, const int* in_sizes, int n_in,
                              void* d_out, int out_size, void* d_ws, size_t ws_size,
                              hipStream_t stream){
  const float* in       = (const float*)d_in[0];
  const float* w_dw     = (const float*)d_in[1];
  const float* w_pw     = (const float*)d_in[2];
  const float* gamma    = (const float*)d_in[3];
  const float* beta     = (const float*)d_in[4];
  const float* w_reduce = (const float*)d_in[5];
  const float* w_span   = (const float*)d_in[6];
  float* out = (float*)d_out;

  _Float16* h16 = (_Float16*)d_ws;                 // 4*16*128*128*4 = 4194304 halfs
  _Float16* r16 = h16 + 4194304;                   // 4*128*128*16   = 1048576 halfs
  _Float16* w16 = r16 + 1048576;                   // 12544 halfs
  float* stats  = (float*)(w16 + 12544);           // 32 floats

  hipMemsetAsync(stats, 0, 32 * sizeof(float), stream);   // graph-capturable
  k_front<<<1024, 256, 0, stream>>>(in, w_dw, w_pw, w_reduce, w_span,
                                    h16, r16, stats, w16);
  dim3 grid(64, 16, 4);
  k_main <<<grid, 256, 0, stream>>>(h16, r16, stats, gamma, beta, w16, out);
}